// Round 1
// baseline (424.465 us; speedup 1.0000x reference)
//
#include <hip/hip_runtime.h>

#define NUM_THRESHOLDS 15

// Native clang vector type — required for __builtin_nontemporal_load/store
// (HIP's float4 is a struct and is rejected by the builtin).
typedef float fvec4 __attribute__((ext_vector_type(4)));

__global__ __launch_bounds__(256) void kmeans_quant_fwd(
    const float* __restrict__ x,
    const float* __restrict__ thresholds,
    const float* __restrict__ alphas,
    const float* __restrict__ b_ptr,
    float* __restrict__ out,
    int n4)  // number of fvec4 elements
{
    // Uniform scalar parameters — broadcast (s_load) reads, cached.
    float th[NUM_THRESHOLDS], al[NUM_THRESHOLDS];
#pragma unroll
    for (int i = 0; i < NUM_THRESHOLDS; ++i) {
        th[i] = thresholds[i];
        al[i] = alphas[i];
    }
    const float b = b_ptr[0];

    const fvec4* __restrict__ x4 = (const fvec4*)x;
    fvec4* __restrict__ o4 = (fvec4*)out;

    // Each thread handles 4 fvec4 (64 B) in 4 coalesced segments of
    // blockDim stride: consecutive lanes -> consecutive 16 B lines within
    // each segment. 4 loads in flight per wave before any compute (MLP=4).
    const int base = blockIdx.x * (blockDim.x * 4) + threadIdx.x;

    const int i0 = base;
    const int i1 = base + blockDim.x;
    const int i2 = base + blockDim.x * 2;
    const int i3 = base + blockDim.x * 3;

    if (i3 < n4) {
        // Fast path (always taken for n = 32*4096*512): issue all 4 loads
        // before any dependent compute.
        fvec4 v0 = __builtin_nontemporal_load(&x4[i0]);
        fvec4 v1 = __builtin_nontemporal_load(&x4[i1]);
        fvec4 v2 = __builtin_nontemporal_load(&x4[i2]);
        fvec4 v3 = __builtin_nontemporal_load(&x4[i3]);

        fvec4 y0 = {b, b, b, b};
        fvec4 y1 = {b, b, b, b};
        fvec4 y2 = {b, b, b, b};
        fvec4 y3 = {b, b, b, b};
        // Keep the exact add order of the reference (sequential over
        // thresholds, adding 0.0f when below) -> bitwise-identical output
        // (current absmax = 0.0).
#pragma unroll
        for (int t = 0; t < NUM_THRESHOLDS; ++t) {
            y0.x += (v0.x >= th[t]) ? al[t] : 0.0f;
            y0.y += (v0.y >= th[t]) ? al[t] : 0.0f;
            y0.z += (v0.z >= th[t]) ? al[t] : 0.0f;
            y0.w += (v0.w >= th[t]) ? al[t] : 0.0f;
            y1.x += (v1.x >= th[t]) ? al[t] : 0.0f;
            y1.y += (v1.y >= th[t]) ? al[t] : 0.0f;
            y1.z += (v1.z >= th[t]) ? al[t] : 0.0f;
            y1.w += (v1.w >= th[t]) ? al[t] : 0.0f;
            y2.x += (v2.x >= th[t]) ? al[t] : 0.0f;
            y2.y += (v2.y >= th[t]) ? al[t] : 0.0f;
            y2.z += (v2.z >= th[t]) ? al[t] : 0.0f;
            y2.w += (v2.w >= th[t]) ? al[t] : 0.0f;
            y3.x += (v3.x >= th[t]) ? al[t] : 0.0f;
            y3.y += (v3.y >= th[t]) ? al[t] : 0.0f;
            y3.z += (v3.z >= th[t]) ? al[t] : 0.0f;
            y3.w += (v3.w >= th[t]) ? al[t] : 0.0f;
        }
        __builtin_nontemporal_store(y0, &o4[i0]);
        __builtin_nontemporal_store(y1, &o4[i1]);
        __builtin_nontemporal_store(y2, &o4[i2]);
        __builtin_nontemporal_store(y3, &o4[i3]);
    } else {
        // Tail path (never taken for the bench shape, kept for safety).
        for (int i = i0; i < n4; i += blockDim.x) {
            fvec4 v = __builtin_nontemporal_load(&x4[i]);
            fvec4 y = {b, b, b, b};
#pragma unroll
            for (int t = 0; t < NUM_THRESHOLDS; ++t) {
                y.x += (v.x >= th[t]) ? al[t] : 0.0f;
                y.y += (v.y >= th[t]) ? al[t] : 0.0f;
                y.z += (v.z >= th[t]) ? al[t] : 0.0f;
                y.w += (v.w >= th[t]) ? al[t] : 0.0f;
            }
            __builtin_nontemporal_store(y, &o4[i]);
        }
    }
}

extern "C" void kernel_launch(void* const* d_in, const int* in_sizes, int n_in,
                              void* d_out, int out_size, void* d_ws, size_t ws_size,
                              hipStream_t stream) {
    // setup_inputs order: x, T, thresholds, alphas, b
    const float* x          = (const float*)d_in[0];
    // d_in[1] is T — only used in backward; unused here.
    const float* thresholds = (const float*)d_in[2];
    const float* alphas     = (const float*)d_in[3];
    const float* b          = (const float*)d_in[4];
    float* out              = (float*)d_out;

    const int n = in_sizes[0];          // 32*4096*512 = 67108864
    const int n4 = n / 4;               // 16777216 fvec4 elements

    const int block = 256;
    const int per_block = block * 4;    // 4 fvec4 (64 B) per thread
    const int grid = (n4 + per_block - 1) / per_block;  // 16384 blocks

    kmeans_quant_fwd<<<grid, block, 0, stream>>>(x, thresholds, alphas, b, out, n4);
}